// Round 11
// baseline (32031.470 us; speedup 1.0000x reference)
//
#include <hip/hip_runtime.h>
#include <cmath>

// RNN: T=2048, B=64, I=H=512, fp32 in/out.
// Phase 1: xw_gemm — f16-MFMA GEMM: xw = x @ W_ih^T + (b_ih+b_hh) -> d_out.
// Phase 2: rnn_scan — 128 WGs = 2 per batch (split h rows 0..255 / 256..511).
//   Each WG: 512 thr (8 waves, 2/SIMD), 256 MFMA/step (1241 cy floor), W half
//   fully register-resident (32 f16x8 frags = 128 regs/wave). Per-step h-half
//   exchange with partner WG via agent-scope atomic qwords + monotonic flag
//   (correct on any XCD mapping; flags zeroed per launch via hipMemsetAsync).
//   h double-buffered in LDS; own chunks computed while remote loads fly.

#define SEQ_T 2048
#define BATCH 64
#define KDIM 512
#define HDIM 512

typedef __fp16 h2v __attribute__((ext_vector_type(2)));
typedef __fp16 f16x8 __attribute__((ext_vector_type(8)));
typedef float f32x4 __attribute__((ext_vector_type(4)));

static __device__ __forceinline__ f16x8 pk8(float4 a, float4 b) {
  h2v p0 = __builtin_amdgcn_cvt_pkrtz(a.x, a.y);
  h2v p1 = __builtin_amdgcn_cvt_pkrtz(a.z, a.w);
  h2v p2 = __builtin_amdgcn_cvt_pkrtz(b.x, b.y);
  h2v p3 = __builtin_amdgcn_cvt_pkrtz(b.z, b.w);
  f16x8 r;
  r[0] = p0[0]; r[1] = p0[1]; r[2] = p1[0]; r[3] = p1[1];
  r[4] = p2[0]; r[5] = p2[1]; r[6] = p3[0]; r[7] = p3[1];
  return r;
}

// ================= Phase 1: f16 MFMA GEMM ===================================
#define G_LDA 72  // f16 units per row (144 B)

#define MFM(mt, nt) \
  d##mt##nt = __builtin_amdgcn_mfma_f32_16x16x32_f16(fa##mt, fb##nt, d##mt##nt, 0, 0, 0);

#define EPI(mt, nt, bb)                                                     \
  {                                                                         \
    int row = m0 + wm + mt * 16 + (l >> 4) * 4;                             \
    int col = n0 + wn + nt * 16 + (l & 15);                                 \
    out[(size_t)(row + 0) * HDIM + col] = d##mt##nt[0] + bb;                \
    out[(size_t)(row + 1) * HDIM + col] = d##mt##nt[1] + bb;                \
    out[(size_t)(row + 2) * HDIM + col] = d##mt##nt[2] + bb;                \
    out[(size_t)(row + 3) * HDIM + col] = d##mt##nt[3] + bb;                \
  }

__global__ __launch_bounds__(256) void xw_gemm(const float* __restrict__ x,
                                               const float* __restrict__ Wih,
                                               const float* __restrict__ bih,
                                               const float* __restrict__ bhh,
                                               float* __restrict__ out) {
  __shared__ __fp16 At[128 * G_LDA];
  __shared__ __fp16 Bt[64 * G_LDA];
  const int tid = threadIdx.x;
  const int l = tid & 63;
  const int w = tid >> 6;
  const int m0 = (blockIdx.x >> 3) * 128;
  const int n0 = (blockIdx.x & 7) * 64;
  const int wm = (w >> 1) * 64;
  const int wn = (w & 1) * 32;

  const float bias0 = bih[n0 + wn + (l & 15)] + bhh[n0 + wn + (l & 15)];
  const float bias1 = bih[n0 + wn + 16 + (l & 15)] + bhh[n0 + wn + 16 + (l & 15)];

  f32x4 d00 = {0,0,0,0}, d01 = {0,0,0,0}, d10 = {0,0,0,0}, d11 = {0,0,0,0};
  f32x4 d20 = {0,0,0,0}, d21 = {0,0,0,0}, d30 = {0,0,0,0}, d31 = {0,0,0,0};

  for (int k0 = 0; k0 < KDIM; k0 += 64) {
    __syncthreads();
#pragma unroll
    for (int p = 0; p < 4; ++p) {
      int idx = tid + p * 256;
      int r = idx >> 3, sg = idx & 7;
      const float* ps = x + (size_t)(m0 + r) * KDIM + k0 + sg * 8;
      *(f16x8*)(At + r * G_LDA + sg * 8) =
          pk8(*(const float4*)ps, *(const float4*)(ps + 4));
    }
#pragma unroll
    for (int p = 0; p < 2; ++p) {
      int idx = tid + p * 256;
      int r = idx >> 3, sg = idx & 7;
      const float* ps = Wih + (size_t)(n0 + r) * KDIM + k0 + sg * 8;
      *(f16x8*)(Bt + r * G_LDA + sg * 8) =
          pk8(*(const float4*)ps, *(const float4*)(ps + 4));
    }
    __syncthreads();
#pragma unroll
    for (int kk = 0; kk < 2; ++kk) {
      const int kc = kk * 32 + (l >> 4) * 8;
      f16x8 fa0 = *(const f16x8*)(At + (wm + 0 * 16 + (l & 15)) * G_LDA + kc);
      f16x8 fa1 = *(const f16x8*)(At + (wm + 1 * 16 + (l & 15)) * G_LDA + kc);
      f16x8 fa2 = *(const f16x8*)(At + (wm + 2 * 16 + (l & 15)) * G_LDA + kc);
      f16x8 fa3 = *(const f16x8*)(At + (wm + 3 * 16 + (l & 15)) * G_LDA + kc);
      f16x8 fb0 = *(const f16x8*)(Bt + (wn + 0 * 16 + (l & 15)) * G_LDA + kc);
      f16x8 fb1 = *(const f16x8*)(Bt + (wn + 1 * 16 + (l & 15)) * G_LDA + kc);
      MFM(0, 0) MFM(1, 0) MFM(2, 0) MFM(3, 0)
      MFM(0, 1) MFM(1, 1) MFM(2, 1) MFM(3, 1)
    }
  }

  EPI(0, 0, bias0) EPI(1, 0, bias0) EPI(2, 0, bias0) EPI(3, 0, bias0)
  EPI(0, 1, bias1) EPI(1, 1, bias1) EPI(2, 1, bias1) EPI(3, 1, bias1)
}

// ================= Phase 2: split MFMA recurrence ===========================
// blk = b + 64*half. WG owns rows [half*256, half*256+256).
// Wave w owns 32 rows: rbase = half*256 + w*32; 2 n-blocks (c=0,1).
// Local chunk q=0..15 -> global k-chunk n=(q+8*half)&15; q=0..7 own-half k,
// q=8..15 remote-half k. B-frag(c,q) = W[rbase+16c+(l&15)][32n+8(l>>4)+e].
// A-frag(q) = h[32n+8(l>>4)+e] replicated -> D rows identical;
// lane l<32 finalizes row rbase+l via d_{l>>4}[0].

#define REPQ(M, c) M(c,0) M(c,1) M(c,2) M(c,3) M(c,4) M(c,5) M(c,6) M(c,7) \
                   M(c,8) M(c,9) M(c,10) M(c,11) M(c,12) M(c,13) M(c,14) M(c,15)

#define DECLB(c, q) f16x8 bf##c##_##q;
#define LOADB(c, q)                                                    \
  {                                                                    \
    const float* p = wrow##c + 32 * ((((q) + half8) & 15));            \
    bf##c##_##q = pk8(*(const float4*)p, *(const float4*)(p + 4));     \
  }

#define MFA(c, q, AR) \
  d##c = __builtin_amdgcn_mfma_f32_16x16x32_f16(AR, bf##c##_##q, d##c, 0, 0, 0);
#define CH2(q, qq, AR)                                                       \
  {                                                                          \
    f16x8 anx = *(const f16x8*)(hcv + ((((qq) + half8) & 15)) * 64 + goff);  \
    MFA(0, q, AR) MFA(1, q, AR)                                              \
    AR = anx;                                                                \
  }
#define CHE(q, AR) { MFA(0, q, AR) MFA(1, q, AR) }

__global__ __attribute__((amdgpu_flat_work_group_size(512, 512),
                          amdgpu_waves_per_eu(2, 2)))
void rnn_scan(const float* __restrict__ Whh, float* __restrict__ io,
              unsigned long long* exch, int* flags) {
  __shared__ __align__(16) __fp16 hbuf[2][512];
  const int tid = threadIdx.x;
  const int blk = blockIdx.x;
  const int b = blk & 63;
  const int half = blk >> 6;
  const int half8 = half * 8;
  const int partner = blk ^ 64;
  const int l = tid & 63;
  const int w = tid >> 6;
  const int m16 = l & 15;
  const int goff = (l >> 4) << 4;
  const int rbase = half * 256 + w * 32;   // wave's first row (global index)
  const int remBase = (half ^ 1) * 256;    // partner's rows
  const int myrow = rbase + (l & 31);

  const float* wrow0 = Whh + (size_t)(rbase + m16) * KDIM + (l >> 4) * 8;
  const float* wrow1 = Whh + (size_t)(rbase + 16 + m16) * KDIM + (l >> 4) * 8;

  // W half: 32 f16x8 frags = 128 regs/wave, fully resident
  REPQ(DECLB, 0) REPQ(DECLB, 1)
  REPQ(LOADB, 0) REPQ(LOADB, 1)

  hbuf[0][tid] = (__fp16)0.f;
  hbuf[1][tid] = (__fp16)0.f;
  __syncthreads();

  float* iorow = io + (size_t)b * HDIM;

  for (int t = 1; t <= SEQ_T; ++t) {
    const char* hcv = (const char*)hbuf[(t - 1) & 1];  // h_{t-1}
    __fp16* hnx = hbuf[t & 1];                         // h_t (own region)

    float uin = iorow[myrow];

    // wait for partner's h_{t-1} (t=1: target 0, passes instantly)
    const int target = t - 1;
    while (__hip_atomic_load(flags + partner, __ATOMIC_ACQUIRE,
                             __HIP_MEMORY_SCOPE_AGENT) < target) {
      __builtin_amdgcn_s_sleep(1);
    }
    // issue remote-half qword loads early (8 lanes/wave x 8 waves = 512 B)
    unsigned long long rq = 0;
    if (t > 1 && l < 8) {
      const unsigned long long* slot = exch + (size_t)(b * 2 + ((t - 1) & 1)) * 128;
      rq = __hip_atomic_load(slot + (remBase >> 2) + w * 8 + l,
                             __ATOMIC_RELAXED, __HIP_MEMORY_SCOPE_AGENT);
    }

    f32x4 d0 = {0.f, 0.f, 0.f, 0.f};
    f32x4 d1 = {0.f, 0.f, 0.f, 0.f};

    // own-half chunks q=0..7 (A from own LDS region, valid since last barrier)
    f16x8 aA = *(const f16x8*)(hcv + ((0 + half8) & 15) * 64 + goff);
    f16x8 aB = *(const f16x8*)(hcv + ((1 + half8) & 15) * 64 + goff);
    CH2(0, 2, aA) CH2(1, 3, aB) CH2(2, 4, aA)
    CH2(3, 5, aB) CH2(4, 6, aA) CH2(5, 7, aB)
    CHE(6, aA) CHE(7, aB)

    // stage remote half into hcv's remote region
    if (t > 1 && l < 8) {
      *(unsigned long long*)((char*)hcv + remBase * 2 + w * 64 + l * 8) = rq;
    }
    asm volatile("s_waitcnt lgkmcnt(0)" ::: "memory");
    __builtin_amdgcn_s_barrier();

    // remote-half chunks q=8..15
    aA = *(const f16x8*)(hcv + ((8 + half8) & 15) * 64 + goff);
    aB = *(const f16x8*)(hcv + ((9 + half8) & 15) * 64 + goff);
    CH2(8, 10, aA) CH2(9, 11, aB) CH2(10, 12, aA)
    CH2(11, 13, aB) CH2(12, 14, aA) CH2(13, 15, aB)
    CHE(14, aA) CHE(15, aB)

    // tail: lane l<32 finalizes row rbase+l
    float zs = (l & 16) ? d1[0] : d0[0];
    float z = uin + zs;
    float e = __expf(2.0f * z);
    float hn = 1.0f - 2.0f * __builtin_amdgcn_rcpf(e + 1.0f);  // tanh(z)

    // pack 4 lanes' h into a qword (lanes l%4==0 hold it)
    float hnn = __shfl_down(hn, 1);
    h2v pp = __builtin_amdgcn_cvt_pkrtz(hn, hnn);
    unsigned int u0 = __builtin_bit_cast(unsigned int, pp);
    unsigned int u1 = __shfl_down(u0, 2);
    unsigned long long q64 = ((unsigned long long)u1 << 32) | u0;

    if (l < 32) {
      iorow[myrow] = hn;
      hnx[myrow] = (__fp16)hn;
      if ((l & 3) == 0) {
        unsigned long long* dslot = exch + (size_t)(b * 2 + (t & 1)) * 128;
        __hip_atomic_store(dslot + (rbase >> 2) + (l >> 2), q64,
                           __ATOMIC_RELAXED, __HIP_MEMORY_SCOPE_AGENT);
      }
    }
    asm volatile("s_waitcnt vmcnt(0) lgkmcnt(0)" ::: "memory");
    __builtin_amdgcn_s_barrier();
    if (tid == 0) {
      __hip_atomic_store(flags + blk, t, __ATOMIC_RELEASE,
                         __HIP_MEMORY_SCOPE_AGENT);
    }
    iorow += (size_t)BATCH * HDIM;
  }
}

extern "C" void kernel_launch(void* const* d_in, const int* in_sizes, int n_in,
                              void* d_out, int out_size, void* d_ws, size_t ws_size,
                              hipStream_t stream) {
  const float* x = (const float*)d_in[0];
  const float* Wih = (const float*)d_in[1];
  const float* Whh = (const float*)d_in[2];
  const float* bih = (const float*)d_in[3];
  const float* bhh = (const float*)d_in[4];
  float* out = (float*)d_out;

  int* flags = (int*)d_ws;                                    // 128 ints
  unsigned long long* exch = (unsigned long long*)((char*)d_ws + 1024);
  // exch: 64 batches x 2 slots x 128 qwords = 128 KB

  hipMemsetAsync(d_ws, 0, 1024, stream);  // zero flags each launch

  const int M = SEQ_T * BATCH;
  dim3 g1((M / 128) * (HDIM / 64));  // 8192
  xw_gemm<<<g1, 256, 0, stream>>>(x, Wih, bih, bhh, out);

  rnn_scan<<<2 * BATCH, 512, 0, stream>>>(Whh, out, exch, flags);
}

// Round 12
// 3559.711 us; speedup vs baseline: 8.9983x; 8.9983x over previous
//
#include <hip/hip_runtime.h>
#include <cmath>

// RNN: T=2048, B=64, I=H=512, fp32 in/out.
// Phase 1: xw_gemm — f16-MFMA GEMM: xw = x @ W_ih^T + (b_ih+b_hh) -> d_out.
// Phase 2: rnn_scan — 64 WGs (1/batch) x 512 thr (8 waves, 2/SIMD).
//   W_hh f16 16 k-chunks: 12 chunks PINNED to AGPRs via asm "+a" (192 AGPR +
//   ~60 arch VGPR = 252 <= 256/wave budget), 4 chunks in LDS (128 KB).
//   ZERO mid-loop L2/HBM traffic for W. h triple-buffered fp16 in LDS,
//   lgkm-only barrier (no vmcnt drain in the step loop).

#define SEQ_T 2048
#define BATCH 64
#define KDIM 512
#define HDIM 512

typedef __fp16 h2v __attribute__((ext_vector_type(2)));
typedef __fp16 f16x8 __attribute__((ext_vector_type(8)));
typedef float f32x4 __attribute__((ext_vector_type(4)));

static __device__ __forceinline__ f16x8 pk8(float4 a, float4 b) {
  h2v p0 = __builtin_amdgcn_cvt_pkrtz(a.x, a.y);
  h2v p1 = __builtin_amdgcn_cvt_pkrtz(a.z, a.w);
  h2v p2 = __builtin_amdgcn_cvt_pkrtz(b.x, b.y);
  h2v p3 = __builtin_amdgcn_cvt_pkrtz(b.z, b.w);
  f16x8 r;
  r[0] = p0[0]; r[1] = p0[1]; r[2] = p1[0]; r[3] = p1[1];
  r[4] = p2[0]; r[5] = p2[1]; r[6] = p3[0]; r[7] = p3[1];
  return r;
}

// ================= Phase 1: f16 MFMA GEMM ===================================
#define G_LDA 72  // f16 units per row (144 B)

#define MFM(mt, nt) \
  d##mt##nt = __builtin_amdgcn_mfma_f32_16x16x32_f16(fa##mt, fb##nt, d##mt##nt, 0, 0, 0);

#define EPI(mt, nt, bb)                                                     \
  {                                                                         \
    int row = m0 + wm + mt * 16 + (l >> 4) * 4;                             \
    int col = n0 + wn + nt * 16 + (l & 15);                                 \
    out[(size_t)(row + 0) * HDIM + col] = d##mt##nt[0] + bb;                \
    out[(size_t)(row + 1) * HDIM + col] = d##mt##nt[1] + bb;                \
    out[(size_t)(row + 2) * HDIM + col] = d##mt##nt[2] + bb;                \
    out[(size_t)(row + 3) * HDIM + col] = d##mt##nt[3] + bb;                \
  }

__global__ __launch_bounds__(256) void xw_gemm(const float* __restrict__ x,
                                               const float* __restrict__ Wih,
                                               const float* __restrict__ bih,
                                               const float* __restrict__ bhh,
                                               float* __restrict__ out) {
  __shared__ __fp16 At[128 * G_LDA];
  __shared__ __fp16 Bt[64 * G_LDA];
  const int tid = threadIdx.x;
  const int l = tid & 63;
  const int w = tid >> 6;
  const int m0 = (blockIdx.x >> 3) * 128;
  const int n0 = (blockIdx.x & 7) * 64;
  const int wm = (w >> 1) * 64;
  const int wn = (w & 1) * 32;

  const float bias0 = bih[n0 + wn + (l & 15)] + bhh[n0 + wn + (l & 15)];
  const float bias1 = bih[n0 + wn + 16 + (l & 15)] + bhh[n0 + wn + 16 + (l & 15)];

  f32x4 d00 = {0,0,0,0}, d01 = {0,0,0,0}, d10 = {0,0,0,0}, d11 = {0,0,0,0};
  f32x4 d20 = {0,0,0,0}, d21 = {0,0,0,0}, d30 = {0,0,0,0}, d31 = {0,0,0,0};

  for (int k0 = 0; k0 < KDIM; k0 += 64) {
    __syncthreads();
#pragma unroll
    for (int p = 0; p < 4; ++p) {
      int idx = tid + p * 256;
      int r = idx >> 3, sg = idx & 7;
      const float* ps = x + (size_t)(m0 + r) * KDIM + k0 + sg * 8;
      *(f16x8*)(At + r * G_LDA + sg * 8) =
          pk8(*(const float4*)ps, *(const float4*)(ps + 4));
    }
#pragma unroll
    for (int p = 0; p < 2; ++p) {
      int idx = tid + p * 256;
      int r = idx >> 3, sg = idx & 7;
      const float* ps = Wih + (size_t)(n0 + r) * KDIM + k0 + sg * 8;
      *(f16x8*)(Bt + r * G_LDA + sg * 8) =
          pk8(*(const float4*)ps, *(const float4*)(ps + 4));
    }
    __syncthreads();
#pragma unroll
    for (int kk = 0; kk < 2; ++kk) {
      const int kc = kk * 32 + (l >> 4) * 8;
      f16x8 fa0 = *(const f16x8*)(At + (wm + 0 * 16 + (l & 15)) * G_LDA + kc);
      f16x8 fa1 = *(const f16x8*)(At + (wm + 1 * 16 + (l & 15)) * G_LDA + kc);
      f16x8 fa2 = *(const f16x8*)(At + (wm + 2 * 16 + (l & 15)) * G_LDA + kc);
      f16x8 fa3 = *(const f16x8*)(At + (wm + 3 * 16 + (l & 15)) * G_LDA + kc);
      f16x8 fb0 = *(const f16x8*)(Bt + (wn + 0 * 16 + (l & 15)) * G_LDA + kc);
      f16x8 fb1 = *(const f16x8*)(Bt + (wn + 1 * 16 + (l & 15)) * G_LDA + kc);
      MFM(0, 0) MFM(1, 0) MFM(2, 0) MFM(3, 0)
      MFM(0, 1) MFM(1, 1) MFM(2, 1) MFM(3, 1)
    }
  }

  EPI(0, 0, bias0) EPI(1, 0, bias0) EPI(2, 0, bias0) EPI(3, 0, bias0)
  EPI(0, 1, bias1) EPI(1, 1, bias1) EPI(2, 1, bias1) EPI(3, 1, bias1)
}

// ================= Phase 2: MFMA recurrence =================================
// wave w owns rows [64w, 64w+64). B-frag(c,n): W[64w+16c+(l&15)][32n+8(l>>4)+e].
// A-frag(n): h[32n+8(l>>4)+e] replicated -> D rows identical.
// Chunks 0..11: AGPR-pinned via asm "+a". Chunks 12..15: LDS (128 KB).

#define REPB(M, c) M(c,0) M(c,1) M(c,2) M(c,3) M(c,4) M(c,5) \
                   M(c,6) M(c,7) M(c,8) M(c,9) M(c,10) M(c,11)

#define DECLB(c, n) f16x8 bf##c##_##n;
#define LOADB(c, n)                                        \
  {                                                        \
    const float* p = wr##c + 32 * n;                       \
    bf##c##_##n = pk8(*(const float4*)p, *(const float4*)(p + 4)); \
  }
#define PINB(c, n) asm volatile("" : "+a"(bf##c##_##n));
#define STOREB(c, n)                                                        \
  {                                                                         \
    const float* p = wr##c + 32 * n;                                        \
    *(f16x8*)(ldsm + (((n) - 12) * 4 + c) * 8192 + (tid << 4)) =            \
        pk8(*(const float4*)p, *(const float4*)(p + 4));                    \
  }

#define MF(c, n) \
  d##c = __builtin_amdgcn_mfma_f32_16x16x32_f16(acur, bf##c##_##n, d##c, 0, 0, 0);
#define MFL(c, n)                                                              \
  {                                                                            \
    f16x8 bl = *(const f16x8*)(ldsm + (((n) - 12) * 4 + c) * 8192 + (tid << 4)); \
    d##c = __builtin_amdgcn_mfma_f32_16x16x32_f16(acur, bl, d##c, 0, 0, 0);    \
  }

#define CH(n, nn)                                                \
  {                                                              \
    f16x8 anx = *(const f16x8*)(hcv + 64 * (nn) + goff);         \
    MF(0, n) MF(1, n) MF(2, n) MF(3, n)                          \
    acur = anx;                                                  \
  }
#define CHL(n, nn)                                               \
  {                                                              \
    f16x8 anx = *(const f16x8*)(hcv + 64 * (nn) + goff);         \
    MFL(0, n) MFL(1, n) MFL(2, n) MFL(3, n)                      \
    acur = anx;                                                  \
  }

#define WLDS_BYTES (16 * 8192)             // 131072 (chunks 12..15)
#define HBUF0 WLDS_BYTES
#define LDS_TOTAL (WLDS_BYTES + 3 * 1024)  // 134144

// lgkm-only barrier: h-buffer ordering without draining VMEM.
#define BAR()                                              \
  asm volatile("s_waitcnt lgkmcnt(0)" ::: "memory");       \
  __builtin_amdgcn_sched_barrier(0);                       \
  __builtin_amdgcn_s_barrier();                            \
  __builtin_amdgcn_sched_barrier(0);

__global__ __attribute__((amdgpu_flat_work_group_size(512, 512),
                          amdgpu_waves_per_eu(2, 2)))
void rnn_scan(const float* __restrict__ Whh, float* __restrict__ io) {
  extern __shared__ __align__(16) char ldsm[];
  const int tid = threadIdx.x;
  const int b = blockIdx.x;
  const int l = tid & 63;
  const int w = tid >> 6;
  const int m16 = l & 15;
  const int gh = l >> 4;
  const int goff = gh << 4;
  const int rb = w << 6;
  const int jo = rb + l;

  const float* wr0 = Whh + (size_t)(rb + 0 + m16) * KDIM + 8 * gh;
  const float* wr1 = Whh + (size_t)(rb + 16 + m16) * KDIM + 8 * gh;
  const float* wr2 = Whh + (size_t)(rb + 32 + m16) * KDIM + 8 * gh;
  const float* wr3 = Whh + (size_t)(rb + 48 + m16) * KDIM + 8 * gh;

  // chunks 0..11: load then PIN into AGPRs (192 AGPR/lane)
  REPB(DECLB, 0) REPB(DECLB, 1) REPB(DECLB, 2) REPB(DECLB, 3)
  REPB(LOADB, 0) REPB(LOADB, 1) REPB(LOADB, 2) REPB(LOADB, 3)
  REPB(PINB, 0)  REPB(PINB, 1)  REPB(PINB, 2)  REPB(PINB, 3)

  // chunks 12..15 in LDS (128 KB)
  STOREB(0, 12) STOREB(1, 12) STOREB(2, 12) STOREB(3, 12)
  STOREB(0, 13) STOREB(1, 13) STOREB(2, 13) STOREB(3, 13)
  STOREB(0, 14) STOREB(1, 14) STOREB(2, 14) STOREB(3, 14)
  STOREB(0, 15) STOREB(1, 15) STOREB(2, 15) STOREB(3, 15)

  if (tid < 512) ((unsigned short*)(ldsm + HBUF0))[tid] = 0;
  __syncthreads();

  char* hcur = ldsm + HBUF0;
  char* hnxt = ldsm + HBUF0 + 1024;
  char* hthr = ldsm + HBUF0 + 2048;

  float* iorow = io + (size_t)b * HDIM;

  for (int t = 0; t < SEQ_T; ++t) {
    float uin = iorow[jo];  // HBM prefetch; consumed in tail

    const char* hcv = hcur;
    f16x8 acur = *(const f16x8*)(hcv + goff);

    f32x4 d0 = {0.f, 0.f, 0.f, 0.f};
    f32x4 d1 = {0.f, 0.f, 0.f, 0.f};
    f32x4 d2 = {0.f, 0.f, 0.f, 0.f};
    f32x4 d3 = {0.f, 0.f, 0.f, 0.f};

    CH(0, 1)  CH(1, 2)   CH(2, 3)   CH(3, 4)
    CH(4, 5)  CH(5, 6)   CH(6, 7)   CH(7, 8)
    CH(8, 9)  CH(9, 10)  CH(10, 11) CH(11, 12)
    CHL(12, 13) CHL(13, 14) CHL(14, 15) CHL(15, 15)

    float za = (l & 16) ? d1[0] : d0[0];
    float zb = (l & 16) ? d3[0] : d2[0];
    float zs = (l & 32) ? zb : za;

    float z = uin + zs;
    float e = __expf(2.0f * z);
    float hn = 1.0f - 2.0f * __builtin_amdgcn_rcpf(e + 1.0f);  // tanh(z)
    iorow[jo] = hn;
    *(__fp16*)(hnxt + 2 * jo) = (__fp16)hn;

    char* tmp = hcur;
    hcur = hnxt; hnxt = hthr; hthr = tmp;
    iorow += (size_t)BATCH * HDIM;
    BAR();
  }
}

extern "C" void kernel_launch(void* const* d_in, const int* in_sizes, int n_in,
                              void* d_out, int out_size, void* d_ws, size_t ws_size,
                              hipStream_t stream) {
  const float* x = (const float*)d_in[0];
  const float* Wih = (const float*)d_in[1];
  const float* Whh = (const float*)d_in[2];
  const float* bih = (const float*)d_in[3];
  const float* bhh = (const float*)d_in[4];
  float* out = (float*)d_out;

  (void)hipFuncSetAttribute((const void*)rnn_scan,
                            hipFuncAttributeMaxDynamicSharedMemorySize,
                            LDS_TOTAL);

  const int M = SEQ_T * BATCH;
  dim3 g1((M / 128) * (HDIM / 64));  // 8192
  xw_gemm<<<g1, 256, 0, stream>>>(x, Wih, bih, bhh, out);

  rnn_scan<<<BATCH, 512, LDS_TOTAL, stream>>>(Whh, out);
}

// Round 13
// 3474.307 us; speedup vs baseline: 9.2195x; 1.0246x over previous
//
#include <hip/hip_runtime.h>
#include <cmath>

// RNN: T=2048, B=64, I=H=512, fp32 in/out.
// Phase 0: w_prep  — pre-convert W_hh chunks 12..15 to f16 frag table in d_ws.
// Phase 1: xw_gemm — f16-MFMA GEMM: xw = x @ W_ih^T + (b_ih+b_hh) -> d_out.
// Phase 2: rnn_scan — 64 WGs (1/batch) x 512 thr (8 waves, 2/SIMD).
//   W mix (proven ceiling): 8 chunks AGPR (128), 4 chunks LDS (128 KB),
//   4 chunks L2-streamed (top-issued). Schedule: LDS chunks interleaved
//   one-per-3-slots with 2-slot-ahead single-buffer prefetch; L2 chunks
//   consumed last. Slot order: 0,1,8, 2,3,9, 4,5,10, 6,7,11, 12,13,14,15.
//   h triple-buffered fp16 in LDS; lgkm-only barrier (no vmcnt drain).

#define SEQ_T 2048
#define BATCH 64
#define KDIM 512
#define HDIM 512

typedef __fp16 h2v __attribute__((ext_vector_type(2)));
typedef __fp16 f16x8 __attribute__((ext_vector_type(8)));
typedef float f32x4 __attribute__((ext_vector_type(4)));

static __device__ __forceinline__ f16x8 pk8(float4 a, float4 b) {
  h2v p0 = __builtin_amdgcn_cvt_pkrtz(a.x, a.y);
  h2v p1 = __builtin_amdgcn_cvt_pkrtz(a.z, a.w);
  h2v p2 = __builtin_amdgcn_cvt_pkrtz(b.x, b.y);
  h2v p3 = __builtin_amdgcn_cvt_pkrtz(b.z, b.w);
  f16x8 r;
  r[0] = p0[0]; r[1] = p0[1]; r[2] = p1[0]; r[3] = p1[1];
  r[4] = p2[0]; r[5] = p2[1]; r[6] = p3[0]; r[7] = p3[1];
  return r;
}

// ================= Phase 0: prep streamed-W f16 fragment table ==============
// frag(n=12..15, c=0..3, w=0..7, l=0..63) = W[64w+16c+(l&15)][32n+8(l>>4)+e]
__global__ __launch_bounds__(256) void w_prep(const float* __restrict__ Whh,
                                              f16x8* __restrict__ ws) {
  int v = blockIdx.x * 256 + threadIdx.x;  // 8192 total
  int l = v & 63, w = (v >> 6) & 7, c = (v >> 9) & 3, n = (v >> 11) + 12;
  int row = 64 * w + 16 * c + (l & 15);
  int col = 32 * n + 8 * (l >> 4);
  const float* p = Whh + (size_t)row * KDIM + col;
  ws[v] = pk8(*(const float4*)p, *(const float4*)(p + 4));
}

// ================= Phase 1: f16 MFMA GEMM ===================================
#define G_LDA 72  // f16 units per row (144 B)

#define MFM(mt, nt) \
  d##mt##nt = __builtin_amdgcn_mfma_f32_16x16x32_f16(fa##mt, fb##nt, d##mt##nt, 0, 0, 0);

#define EPI(mt, nt, bb)                                                     \
  {                                                                         \
    int row = m0 + wm + mt * 16 + (l >> 4) * 4;                             \
    int col = n0 + wn + nt * 16 + (l & 15);                                 \
    out[(size_t)(row + 0) * HDIM + col] = d##mt##nt[0] + bb;                \
    out[(size_t)(row + 1) * HDIM + col] = d##mt##nt[1] + bb;                \
    out[(size_t)(row + 2) * HDIM + col] = d##mt##nt[2] + bb;                \
    out[(size_t)(row + 3) * HDIM + col] = d##mt##nt[3] + bb;                \
  }

__global__ __launch_bounds__(256) void xw_gemm(const float* __restrict__ x,
                                               const float* __restrict__ Wih,
                                               const float* __restrict__ bih,
                                               const float* __restrict__ bhh,
                                               float* __restrict__ out) {
  __shared__ __fp16 At[128 * G_LDA];
  __shared__ __fp16 Bt[64 * G_LDA];
  const int tid = threadIdx.x;
  const int l = tid & 63;
  const int w = tid >> 6;
  const int m0 = (blockIdx.x >> 3) * 128;
  const int n0 = (blockIdx.x & 7) * 64;
  const int wm = (w >> 1) * 64;
  const int wn = (w & 1) * 32;

  const float bias0 = bih[n0 + wn + (l & 15)] + bhh[n0 + wn + (l & 15)];
  const float bias1 = bih[n0 + wn + 16 + (l & 15)] + bhh[n0 + wn + 16 + (l & 15)];

  f32x4 d00 = {0,0,0,0}, d01 = {0,0,0,0}, d10 = {0,0,0,0}, d11 = {0,0,0,0};
  f32x4 d20 = {0,0,0,0}, d21 = {0,0,0,0}, d30 = {0,0,0,0}, d31 = {0,0,0,0};

  for (int k0 = 0; k0 < KDIM; k0 += 64) {
    __syncthreads();
#pragma unroll
    for (int p = 0; p < 4; ++p) {
      int idx = tid + p * 256;
      int r = idx >> 3, sg = idx & 7;
      const float* ps = x + (size_t)(m0 + r) * KDIM + k0 + sg * 8;
      *(f16x8*)(At + r * G_LDA + sg * 8) =
          pk8(*(const float4*)ps, *(const float4*)(ps + 4));
    }
#pragma unroll
    for (int p = 0; p < 2; ++p) {
      int idx = tid + p * 256;
      int r = idx >> 3, sg = idx & 7;
      const float* ps = Wih + (size_t)(n0 + r) * KDIM + k0 + sg * 8;
      *(f16x8*)(Bt + r * G_LDA + sg * 8) =
          pk8(*(const float4*)ps, *(const float4*)(ps + 4));
    }
    __syncthreads();
#pragma unroll
    for (int kk = 0; kk < 2; ++kk) {
      const int kc = kk * 32 + (l >> 4) * 8;
      f16x8 fa0 = *(const f16x8*)(At + (wm + 0 * 16 + (l & 15)) * G_LDA + kc);
      f16x8 fa1 = *(const f16x8*)(At + (wm + 1 * 16 + (l & 15)) * G_LDA + kc);
      f16x8 fa2 = *(const f16x8*)(At + (wm + 2 * 16 + (l & 15)) * G_LDA + kc);
      f16x8 fa3 = *(const f16x8*)(At + (wm + 3 * 16 + (l & 15)) * G_LDA + kc);
      f16x8 fb0 = *(const f16x8*)(Bt + (wn + 0 * 16 + (l & 15)) * G_LDA + kc);
      f16x8 fb1 = *(const f16x8*)(Bt + (wn + 1 * 16 + (l & 15)) * G_LDA + kc);
      MFM(0, 0) MFM(1, 0) MFM(2, 0) MFM(3, 0)
      MFM(0, 1) MFM(1, 1) MFM(2, 1) MFM(3, 1)
    }
  }

  EPI(0, 0, bias0) EPI(1, 0, bias0) EPI(2, 0, bias0) EPI(3, 0, bias0)
  EPI(0, 1, bias1) EPI(1, 1, bias1) EPI(2, 1, bias1) EPI(3, 1, bias1)
}

// ================= Phase 2: MFMA recurrence =================================
// wave w owns rows [64w, 64w+64). B-frag(c,n): W[64w+16c+(l&15)][32n+8(l>>4)+e].
// A-frag(n): h[32n+8(l>>4)+e] replicated -> D rows identical.
// n=0..7 AGPR; n=8..11 LDS (interleaved slots, 2-slot-ahead prefetch);
// n=12..15 L2 stream (top-issued, consumed last).

#define REPB(M, c) M(c,0) M(c,1) M(c,2) M(c,3) M(c,4) M(c,5) M(c,6) M(c,7)

#define DECLB(c, n) f16x8 bf##c##_##n;
#define LOADB(c, n)                                        \
  {                                                        \
    const float* p = wr##c + 32 * n;                       \
    bf##c##_##n = pk8(*(const float4*)p, *(const float4*)(p + 4)); \
  }
#define STOREB(c, n)                                                        \
  {                                                                         \
    const float* p = wr##c + 32 * n;                                        \
    *(f16x8*)(ldsm + (((n) - 8) * 4 + c) * 8192 + (tid << 4)) =             \
        pk8(*(const float4*)p, *(const float4*)(p + 4));                    \
  }

#define DECLS(n) f16x8 sv0_##n, sv1_##n, sv2_##n, sv3_##n;
#define LOADS(n)                                   \
  sv0_##n = wsp[((n - 12) * 4 + 0) * 512];         \
  sv1_##n = wsp[((n - 12) * 4 + 1) * 512];         \
  sv2_##n = wsp[((n - 12) * 4 + 2) * 512];         \
  sv3_##n = wsp[((n - 12) * 4 + 3) * 512];

#define ISSUE_WL(n)                                                        \
  wl0 = *(const f16x8*)(ldsm + (((n) - 8) * 4 + 0) * 8192 + (tid << 4));   \
  wl1 = *(const f16x8*)(ldsm + (((n) - 8) * 4 + 1) * 8192 + (tid << 4));   \
  wl2 = *(const f16x8*)(ldsm + (((n) - 8) * 4 + 2) * 8192 + (tid << 4));   \
  wl3 = *(const f16x8*)(ldsm + (((n) - 8) * 4 + 3) * 8192 + (tid << 4));

#define MF(c, n) \
  d##c = __builtin_amdgcn_mfma_f32_16x16x32_f16(acur, bf##c##_##n, d##c, 0, 0, 0);
#define MS(c, n) \
  d##c = __builtin_amdgcn_mfma_f32_16x16x32_f16(acur, sv##c##_##n, d##c, 0, 0, 0);

// AGPR chunk slot: 4 MFMA + A-prefetch for chunk nn
#define CH(n, nn)                                                \
  {                                                              \
    f16x8 anx = *(const f16x8*)(hcv + 64 * (nn) + goff);         \
    MF(0, n) MF(1, n) MF(2, n) MF(3, n)                          \
    acur = anx;                                                  \
  }
// LDS chunk slot: consume wl buffer, A-prefetch chunk nn
#define CHW(nn)                                                              \
  {                                                                          \
    f16x8 anx = *(const f16x8*)(hcv + 64 * (nn) + goff);                     \
    d0 = __builtin_amdgcn_mfma_f32_16x16x32_f16(acur, wl0, d0, 0, 0, 0);     \
    d1 = __builtin_amdgcn_mfma_f32_16x16x32_f16(acur, wl1, d1, 0, 0, 0);     \
    d2 = __builtin_amdgcn_mfma_f32_16x16x32_f16(acur, wl2, d2, 0, 0, 0);     \
    d3 = __builtin_amdgcn_mfma_f32_16x16x32_f16(acur, wl3, d3, 0, 0, 0);     \
    acur = anx;                                                              \
  }
// L2 chunk slot
#define CST(n, nn)                                               \
  {                                                              \
    f16x8 anx = *(const f16x8*)(hcv + 64 * (nn) + goff);         \
    MS(0, n) MS(1, n) MS(2, n) MS(3, n)                          \
    acur = anx;                                                  \
  }

#define WLDS_BYTES (16 * 8192)             // 131072 (chunks 8..11)
#define HBUF0 WLDS_BYTES
#define LDS_TOTAL (WLDS_BYTES + 3 * 1024)  // 134144

// lgkm-only barrier: h-buffer ordering without draining VMEM.
#define BAR()                                              \
  asm volatile("s_waitcnt lgkmcnt(0)" ::: "memory");       \
  __builtin_amdgcn_sched_barrier(0);                       \
  __builtin_amdgcn_s_barrier();                            \
  __builtin_amdgcn_sched_barrier(0);

__global__ __attribute__((amdgpu_flat_work_group_size(512, 512),
                          amdgpu_waves_per_eu(2, 2)))
void rnn_scan(const float* __restrict__ Whh, const f16x8* __restrict__ ws,
              float* __restrict__ io) {
  extern __shared__ __align__(16) char ldsm[];
  const int tid = threadIdx.x;
  const int b = blockIdx.x;
  const int l = tid & 63;
  const int w = tid >> 6;
  const int m16 = l & 15;
  const int gh = l >> 4;
  const int goff = gh << 4;
  const int rb = w << 6;
  const int jo = rb + l;

  const float* wr0 = Whh + (size_t)(rb + 0 + m16) * KDIM + 8 * gh;
  const float* wr1 = Whh + (size_t)(rb + 16 + m16) * KDIM + 8 * gh;
  const float* wr2 = Whh + (size_t)(rb + 32 + m16) * KDIM + 8 * gh;
  const float* wr3 = Whh + (size_t)(rb + 48 + m16) * KDIM + 8 * gh;

  // chunks 0..7 -> AGPR side of the unified file (proven 128-AGPR capacity)
  REPB(DECLB, 0) REPB(DECLB, 1) REPB(DECLB, 2) REPB(DECLB, 3)
  REPB(LOADB, 0) REPB(LOADB, 1) REPB(LOADB, 2) REPB(LOADB, 3)

  // chunks 8..11 -> LDS (128 KB)
  STOREB(0, 8)  STOREB(1, 8)  STOREB(2, 8)  STOREB(3, 8)
  STOREB(0, 9)  STOREB(1, 9)  STOREB(2, 9)  STOREB(3, 9)
  STOREB(0, 10) STOREB(1, 10) STOREB(2, 10) STOREB(3, 10)
  STOREB(0, 11) STOREB(1, 11) STOREB(2, 11) STOREB(3, 11)

  const f16x8* wsp = ws + (w * 64 + l);

  if (tid < 512) ((unsigned short*)(ldsm + HBUF0))[tid] = 0;
  __syncthreads();

  char* hcur = ldsm + HBUF0;
  char* hnxt = ldsm + HBUF0 + 1024;
  char* hthr = ldsm + HBUF0 + 2048;

  float* iorow = io + (size_t)b * HDIM;

  DECLS(12) DECLS(13) DECLS(14) DECLS(15)
  f16x8 wl0, wl1, wl2, wl3;

  for (int t = 0; t < SEQ_T; ++t) {
    float uin = iorow[jo];     // HBM prefetch; consumed in tail

    // L2-streamed chunks: issue all at step top (BW drains under MFMA)
    LOADS(12) LOADS(13) LOADS(14) LOADS(15)

    const char* hcv = hcur;
    f16x8 acur = *(const f16x8*)(hcv + goff);

    f32x4 d0 = {0.f, 0.f, 0.f, 0.f};
    f32x4 d1 = {0.f, 0.f, 0.f, 0.f};
    f32x4 d2 = {0.f, 0.f, 0.f, 0.f};
    f32x4 d3 = {0.f, 0.f, 0.f, 0.f};

    // slot order: 0,1,8, 2,3,9, 4,5,10, 6,7,11, 12,13,14,15
    ISSUE_WL(8)
    CH(0, 1)   CH(1, 8)
    CHW(2)     ISSUE_WL(9)
    CH(2, 3)   CH(3, 9)
    CHW(4)     ISSUE_WL(10)
    CH(4, 5)   CH(5, 10)
    CHW(6)     ISSUE_WL(11)
    CH(6, 7)   CH(7, 11)
    CHW(12)
    CST(12, 13) CST(13, 14) CST(14, 15) CST(15, 15)

    float za = (l & 16) ? d1[0] : d0[0];
    float zb = (l & 16) ? d3[0] : d2[0];
    float zs = (l & 32) ? zb : za;

    float z = uin + zs;
    float e = __expf(2.0f * z);
    float hn = 1.0f - 2.0f * __builtin_amdgcn_rcpf(e + 1.0f);  // tanh(z)
    iorow[jo] = hn;
    *(__fp16*)(hnxt + 2 * jo) = (__fp16)hn;

    char* tmp = hcur;
    hcur = hnxt; hnxt = hthr; hthr = tmp;
    iorow += (size_t)BATCH * HDIM;
    BAR();
  }
}

extern "C" void kernel_launch(void* const* d_in, const int* in_sizes, int n_in,
                              void* d_out, int out_size, void* d_ws, size_t ws_size,
                              hipStream_t stream) {
  const float* x = (const float*)d_in[0];
  const float* Wih = (const float*)d_in[1];
  const float* Whh = (const float*)d_in[2];
  const float* bih = (const float*)d_in[3];
  const float* bhh = (const float*)d_in[4];
  float* out = (float*)d_out;
  f16x8* ws = (f16x8*)d_ws;

  (void)hipFuncSetAttribute((const void*)rnn_scan,
                            hipFuncAttributeMaxDynamicSharedMemorySize,
                            LDS_TOTAL);

  w_prep<<<32, 256, 0, stream>>>(Whh, ws);

  const int M = SEQ_T * BATCH;
  dim3 g1((M / 128) * (HDIM / 64));  // 8192
  xw_gemm<<<g1, 256, 0, stream>>>(x, Wih, bih, bhh, out);

  rnn_scan<<<BATCH, 512, LDS_TOTAL, stream>>>(Whh, ws, out);
}

// Round 14
// 3361.422 us; speedup vs baseline: 9.5291x; 1.0336x over previous
//
#include <hip/hip_runtime.h>
#include <cmath>

// RNN: T=2048, B=64, I=H=512, fp32 in/out.
// Phase 0: w_prep  — pre-convert W_hh chunks 8..11 to f16 frag table in d_ws.
// Phase 1: xw_gemm — f16-MFMA GEMM: xw = x @ W_ih^T + (b_ih+b_hh) -> d_out.
// Phase 2: rnn_scan — R7-exact structure (measured best, 3100 us), with the
//   compiler-sunk chunks 8..11 sourced from the f16 table (halves their
//   per-step L2 bytes, removes per-step cvt). 12 register-intent chunks
//   (8 stay AGPR, 4 sink to cheap f16 reloads) + 4 chunks LDS (128 KB).
//   h triple-buffered fp16 in LDS, ONE __syncthreads per step.

#define SEQ_T 2048
#define BATCH 64
#define KDIM 512
#define HDIM 512

typedef __fp16 h2v __attribute__((ext_vector_type(2)));
typedef __fp16 f16x8 __attribute__((ext_vector_type(8)));
typedef float f32x4 __attribute__((ext_vector_type(4)));

static __device__ __forceinline__ f16x8 pk8(float4 a, float4 b) {
  h2v p0 = __builtin_amdgcn_cvt_pkrtz(a.x, a.y);
  h2v p1 = __builtin_amdgcn_cvt_pkrtz(a.z, a.w);
  h2v p2 = __builtin_amdgcn_cvt_pkrtz(b.x, b.y);
  h2v p3 = __builtin_amdgcn_cvt_pkrtz(b.z, b.w);
  f16x8 r;
  r[0] = p0[0]; r[1] = p0[1]; r[2] = p1[0]; r[3] = p1[1];
  r[4] = p2[0]; r[5] = p2[1]; r[6] = p3[0]; r[7] = p3[1];
  return r;
}

// ================= Phase 0: prep f16 fragment table (chunks 8..11) ==========
// frag(n=8..11, c=0..3, w=0..7, l=0..63) = W[64w+16c+(l&15)][32n+8(l>>4)+e]
// ws index = ((n-8)*4 + c)*512 + w*64 + l   (f16x8 units)
__global__ __launch_bounds__(256) void w_prep(const float* __restrict__ Whh,
                                              f16x8* __restrict__ ws) {
  int v = blockIdx.x * 256 + threadIdx.x;  // 8192 total
  int l = v & 63, w = (v >> 6) & 7, c = (v >> 9) & 3, n = (v >> 11) + 8;
  int row = 64 * w + 16 * c + (l & 15);
  int col = 32 * n + 8 * (l >> 4);
  const float* p = Whh + (size_t)row * KDIM + col;
  ws[v] = pk8(*(const float4*)p, *(const float4*)(p + 4));
}

// ================= Phase 1: f16 MFMA GEMM ===================================
#define G_LDA 72  // f16 units per row (144 B)

#define MFM(mt, nt) \
  d##mt##nt = __builtin_amdgcn_mfma_f32_16x16x32_f16(fa##mt, fb##nt, d##mt##nt, 0, 0, 0);

#define EPI(mt, nt, bb)                                                     \
  {                                                                         \
    int row = m0 + wm + mt * 16 + (l >> 4) * 4;                             \
    int col = n0 + wn + nt * 16 + (l & 15);                                 \
    out[(size_t)(row + 0) * HDIM + col] = d##mt##nt[0] + bb;                \
    out[(size_t)(row + 1) * HDIM + col] = d##mt##nt[1] + bb;                \
    out[(size_t)(row + 2) * HDIM + col] = d##mt##nt[2] + bb;                \
    out[(size_t)(row + 3) * HDIM + col] = d##mt##nt[3] + bb;                \
  }

__global__ __launch_bounds__(256) void xw_gemm(const float* __restrict__ x,
                                               const float* __restrict__ Wih,
                                               const float* __restrict__ bih,
                                               const float* __restrict__ bhh,
                                               float* __restrict__ out) {
  __shared__ __fp16 At[128 * G_LDA];
  __shared__ __fp16 Bt[64 * G_LDA];
  const int tid = threadIdx.x;
  const int l = tid & 63;
  const int w = tid >> 6;
  const int m0 = (blockIdx.x >> 3) * 128;
  const int n0 = (blockIdx.x & 7) * 64;
  const int wm = (w >> 1) * 64;
  const int wn = (w & 1) * 32;

  const float bias0 = bih[n0 + wn + (l & 15)] + bhh[n0 + wn + (l & 15)];
  const float bias1 = bih[n0 + wn + 16 + (l & 15)] + bhh[n0 + wn + 16 + (l & 15)];

  f32x4 d00 = {0,0,0,0}, d01 = {0,0,0,0}, d10 = {0,0,0,0}, d11 = {0,0,0,0};
  f32x4 d20 = {0,0,0,0}, d21 = {0,0,0,0}, d30 = {0,0,0,0}, d31 = {0,0,0,0};

  for (int k0 = 0; k0 < KDIM; k0 += 64) {
    __syncthreads();
#pragma unroll
    for (int p = 0; p < 4; ++p) {
      int idx = tid + p * 256;
      int r = idx >> 3, sg = idx & 7;
      const float* ps = x + (size_t)(m0 + r) * KDIM + k0 + sg * 8;
      *(f16x8*)(At + r * G_LDA + sg * 8) =
          pk8(*(const float4*)ps, *(const float4*)(ps + 4));
    }
#pragma unroll
    for (int p = 0; p < 2; ++p) {
      int idx = tid + p * 256;
      int r = idx >> 3, sg = idx & 7;
      const float* ps = Wih + (size_t)(n0 + r) * KDIM + k0 + sg * 8;
      *(f16x8*)(Bt + r * G_LDA + sg * 8) =
          pk8(*(const float4*)ps, *(const float4*)(ps + 4));
    }
    __syncthreads();
#pragma unroll
    for (int kk = 0; kk < 2; ++kk) {
      const int kc = kk * 32 + (l >> 4) * 8;
      f16x8 fa0 = *(const f16x8*)(At + (wm + 0 * 16 + (l & 15)) * G_LDA + kc);
      f16x8 fa1 = *(const f16x8*)(At + (wm + 1 * 16 + (l & 15)) * G_LDA + kc);
      f16x8 fa2 = *(const f16x8*)(At + (wm + 2 * 16 + (l & 15)) * G_LDA + kc);
      f16x8 fa3 = *(const f16x8*)(At + (wm + 3 * 16 + (l & 15)) * G_LDA + kc);
      f16x8 fb0 = *(const f16x8*)(Bt + (wn + 0 * 16 + (l & 15)) * G_LDA + kc);
      f16x8 fb1 = *(const f16x8*)(Bt + (wn + 1 * 16 + (l & 15)) * G_LDA + kc);
      MFM(0, 0) MFM(1, 0) MFM(2, 0) MFM(3, 0)
      MFM(0, 1) MFM(1, 1) MFM(2, 1) MFM(3, 1)
    }
  }

  EPI(0, 0, bias0) EPI(1, 0, bias0) EPI(2, 0, bias0) EPI(3, 0, bias0)
  EPI(0, 1, bias1) EPI(1, 1, bias1) EPI(2, 1, bias1) EPI(3, 1, bias1)
}

// ================= Phase 2: MFMA recurrence (R7 structure) ==================
// wave w owns rows [64w, 64w+64). B-frag(c,n): W[64w+16c+(l&15)][32n+8(l>>4)+e].
// A-frag(n): h[32n+8(l>>4)+e] replicated -> D rows identical.
// Chunks 0..7: register-intent from Whh fp32 (stay AGPR-resident).
// Chunks 8..11: register-intent from f16 ws table (compiler sinks these ->
//               cheap per-step f16 reloads, half the bytes of R7's fp32+cvt).
// Chunks 12..15: LDS (128 KB).

#define REPB(M, c) M(c,0) M(c,1) M(c,2) M(c,3) M(c,4) M(c,5) M(c,6) M(c,7)
#define REPW(M, c) M(c,8) M(c,9) M(c,10) M(c,11)

#define DECLB(c, n) f16x8 bf##c##_##n;
#define LOADB(c, n)                                        \
  {                                                        \
    const float* p = wr##c + 32 * n;                       \
    bf##c##_##n = pk8(*(const float4*)p, *(const float4*)(p + 4)); \
  }
#define LOADW(c, n) bf##c##_##n = wsp[(((n) - 8) * 4 + (c)) * 512];
#define STOREB(c, n)                                                        \
  {                                                                         \
    const float* p = wr##c + 32 * n;                                        \
    *(f16x8*)(ldsm + (((n) - 12) * 4 + c) * 8192 + (tid << 4)) =            \
        pk8(*(const float4*)p, *(const float4*)(p + 4));                    \
  }

#define MF(c, n) \
  d##c = __builtin_amdgcn_mfma_f32_16x16x32_f16(acur, bf##c##_##n, d##c, 0, 0, 0);
#define MFL(c, n)                                                              \
  {                                                                            \
    f16x8 bl = *(const f16x8*)(ldsm + (((n) - 12) * 4 + c) * 8192 + (tid << 4)); \
    d##c = __builtin_amdgcn_mfma_f32_16x16x32_f16(acur, bl, d##c, 0, 0, 0);    \
  }

#define CH(n, nn)                                                \
  {                                                              \
    f16x8 anx = *(const f16x8*)(hcv + 64 * (nn) + goff);         \
    MF(0, n) MF(1, n) MF(2, n) MF(3, n)                          \
    acur = anx;                                                  \
  }
#define CHL(n, nn)                                               \
  {                                                              \
    f16x8 anx = *(const f16x8*)(hcv + 64 * (nn) + goff);         \
    MFL(0, n) MFL(1, n) MFL(2, n) MFL(3, n)                      \
    acur = anx;                                                  \
  }

#define WLDS_BYTES (16 * 8192)             // 131072 (chunks 12..15)
#define HBUF0 WLDS_BYTES
#define LDS_TOTAL (WLDS_BYTES + 3 * 1024)  // 134144

__global__ __attribute__((amdgpu_flat_work_group_size(512, 512),
                          amdgpu_waves_per_eu(2, 2)))
void rnn_scan(const float* __restrict__ Whh, const f16x8* __restrict__ ws,
              float* __restrict__ io) {
  extern __shared__ __align__(16) char ldsm[];
  const int tid = threadIdx.x;
  const int b = blockIdx.x;
  const int l = tid & 63;
  const int w = tid >> 6;
  const int m16 = l & 15;
  const int gh = l >> 4;
  const int goff = gh << 4;
  const int rb = w << 6;
  const int jo = rb + l;

  const float* wr0 = Whh + (size_t)(rb + 0 + m16) * KDIM + 8 * gh;
  const float* wr1 = Whh + (size_t)(rb + 16 + m16) * KDIM + 8 * gh;
  const float* wr2 = Whh + (size_t)(rb + 32 + m16) * KDIM + 8 * gh;
  const float* wr3 = Whh + (size_t)(rb + 48 + m16) * KDIM + 8 * gh;
  const f16x8* wsp = ws + (w * 64 + l);

  // chunks 0..7 from fp32 (load-once, AGPR); chunks 8..11 from f16 table
  // (register-intent; compiler sinks these to cheap per-step f16 reloads)
  REPB(DECLB, 0) REPB(DECLB, 1) REPB(DECLB, 2) REPB(DECLB, 3)
  REPW(DECLB, 0) REPW(DECLB, 1) REPW(DECLB, 2) REPW(DECLB, 3)
  REPB(LOADB, 0) REPB(LOADB, 1) REPB(LOADB, 2) REPB(LOADB, 3)
  REPW(LOADW, 0) REPW(LOADW, 1) REPW(LOADW, 2) REPW(LOADW, 3)

  // chunks 12..15 in LDS (128 KB)
  STOREB(0, 12) STOREB(1, 12) STOREB(2, 12) STOREB(3, 12)
  STOREB(0, 13) STOREB(1, 13) STOREB(2, 13) STOREB(3, 13)
  STOREB(0, 14) STOREB(1, 14) STOREB(2, 14) STOREB(3, 14)
  STOREB(0, 15) STOREB(1, 15) STOREB(2, 15) STOREB(3, 15)

  if (tid < 512) ((unsigned short*)(ldsm + HBUF0))[tid] = 0;
  __syncthreads();

  char* hcur = ldsm + HBUF0;
  char* hnxt = ldsm + HBUF0 + 1024;
  char* hthr = ldsm + HBUF0 + 2048;

  float* iorow = io + (size_t)b * HDIM;

  for (int t = 0; t < SEQ_T; ++t) {
    float uin = iorow[jo];  // HBM prefetch; consumed in tail

    const char* hcv = hcur;
    f16x8 acur = *(const f16x8*)(hcv + goff);

    f32x4 d0 = {0.f, 0.f, 0.f, 0.f};
    f32x4 d1 = {0.f, 0.f, 0.f, 0.f};
    f32x4 d2 = {0.f, 0.f, 0.f, 0.f};
    f32x4 d3 = {0.f, 0.f, 0.f, 0.f};

    CH(0, 1)  CH(1, 2)   CH(2, 3)   CH(3, 4)
    CH(4, 5)  CH(5, 6)   CH(6, 7)   CH(7, 8)
    CH(8, 9)  CH(9, 10)  CH(10, 11) CH(11, 12)
    CHL(12, 13) CHL(13, 14) CHL(14, 15) CHL(15, 15)

    float za = (l & 16) ? d1[0] : d0[0];
    float zb = (l & 16) ? d3[0] : d2[0];
    float zs = (l & 32) ? zb : za;

    float z = uin + zs;
    float e = __expf(2.0f * z);
    float hn = 1.0f - 2.0f * __builtin_amdgcn_rcpf(e + 1.0f);  // tanh(z)
    iorow[jo] = hn;
    *(__fp16*)(hnxt + 2 * jo) = (__fp16)hn;

    char* tmp = hcur;
    hcur = hnxt; hnxt = hthr; hthr = tmp;
    iorow += (size_t)BATCH * HDIM;
    __syncthreads();
  }
}

extern "C" void kernel_launch(void* const* d_in, const int* in_sizes, int n_in,
                              void* d_out, int out_size, void* d_ws, size_t ws_size,
                              hipStream_t stream) {
  const float* x = (const float*)d_in[0];
  const float* Wih = (const float*)d_in[1];
  const float* Whh = (const float*)d_in[2];
  const float* bih = (const float*)d_in[3];
  const float* bhh = (const float*)d_in[4];
  float* out = (float*)d_out;
  f16x8* ws = (f16x8*)d_ws;

  (void)hipFuncSetAttribute((const void*)rnn_scan,
                            hipFuncAttributeMaxDynamicSharedMemorySize,
                            LDS_TOTAL);

  w_prep<<<32, 256, 0, stream>>>(Whh, ws);

  const int M = SEQ_T * BATCH;
  dim3 g1((M / 128) * (HDIM / 64));  // 8192
  xw_gemm<<<g1, 256, 0, stream>>>(x, Wih, bih, bhh, out);

  rnn_scan<<<BATCH, 512, LDS_TOTAL, stream>>>(Whh, ws, out);
}